// Round 1
// baseline (169.523 us; speedup 1.0000x reference)
//
#include <hip/hip_runtime.h>
#include <hip/hip_bf16.h>

#define NROWS 16384
#define DIM 64

static constexpr float TAU = 0.28f;
static constexpr float EPS = 1e-8f;
// exp(x/TAU) = exp2(x * EXP2_SCALE)
static constexpr float EXP2_SCALE = (float)(1.0 / (0.28 * 0.6931471805599453));

using short8 = __attribute__((ext_vector_type(8))) short;
using f32x4  = __attribute__((ext_vector_type(4))) float;

// Kernel 1: per-row L2 normalize; emit A = bf16(EXP2_SCALE * u_norm),
// W = bf16(u_norm + i_norm), p[n] = (u_norm . i_norm)/TAU.
// One wave per row (64 lanes <-> 64 dims), 4 rows per 256-thread block.
__global__ __launch_bounds__(256) void prep_kernel(
    const float* __restrict__ u, const float* __restrict__ v,
    __hip_bfloat16* __restrict__ a_out, __hip_bfloat16* __restrict__ w_out,
    float* __restrict__ p_out)
{
    const int lane = threadIdx.x & 63;
    const int wv   = threadIdx.x >> 6;
    const int row  = blockIdx.x * 4 + wv;

    const float uu = u[row * DIM + lane];
    const float ii = v[row * DIM + lane];
    float su = uu * uu, si = ii * ii, sd = uu * ii;
#pragma unroll
    for (int m = 1; m < 64; m <<= 1) {
        su += __shfl_xor(su, m, 64);
        si += __shfl_xor(si, m, 64);
        sd += __shfl_xor(sd, m, 64);
    }
    const float inv_u = 1.0f / fmaxf(sqrtf(su), 1e-12f);
    const float inv_i = 1.0f / fmaxf(sqrtf(si), 1e-12f);
    const float un = uu * inv_u;
    const float in = ii * inv_i;
    a_out[row * DIM + lane] = __float2bfloat16(EXP2_SCALE * un);
    w_out[row * DIM + lane] = __float2bfloat16(un + in);
    if (lane == 0) p_out[row] = sd * inv_u * inv_i * (1.0f / TAU);
}

// Kernel 2: fused GEMM + exp + row-sum.
// Grid: 512 blocks = 256 row-blocks (64 rows each) x 2 column halves.
// Block: 256 threads = 4 waves; every wave owns all 64 rows (8 A-frags in
// registers) and 2 of the 8 column sub-tiles per 128-col LDS-staged W tile.
// LDS row stride 88 ushorts (176 B): 16B-aligned, worst ds_read_b128
// aliasing is 2-way (free on gfx950).
__global__ __launch_bounds__(256, 2) void score_kernel(
    const __hip_bfloat16* __restrict__ A, const __hip_bfloat16* __restrict__ W,
    float* __restrict__ total)
{
    __shared__ alignas(16) ushort wlds[128 * 88];

    const int tid  = threadIdx.x;
    const int lane = tid & 63;
    const int wv   = tid >> 6;
    const int l15  = lane & 15;
    const int quad = lane >> 4;
    const int rb   = blockIdx.x >> 1;
    const int cs   = blockIdx.x & 1;
    const int rowbase = rb * 64;
    const int col0 = cs * (NROWS / 2);

    const ushort* Au = (const ushort*)A;
    const ushort* Wu = (const ushort*)W;

    // A fragments: rows rowbase + rs*16 + l15, k = kk*32 + quad*8 + [0..7]
    short8 afrag[4][2];
#pragma unroll
    for (int rs = 0; rs < 4; rs++)
#pragma unroll
        for (int kk = 0; kk < 2; kk++)
            afrag[rs][kk] = *(const short8*)(
                Au + (size_t)(rowbase + rs * 16 + l15) * DIM + kk * 32 + quad * 8);

    float rowsum[4][4];
#pragma unroll
    for (int rs = 0; rs < 4; rs++)
#pragma unroll
        for (int r = 0; r < 4; r++) rowsum[rs][r] = 0.0f;

    for (int it = 0; it < (NROWS / 2) / 128; it++) {
        const int jbase = col0 + it * 128;
        // Stage 128 rows of W (128 B each) into LDS: 1024 16B chunks.
#pragma unroll
        for (int q = 0; q < 4; q++) {
            const int g = tid + 256 * q;
            const int j = g >> 3, c = g & 7;
            *(uint4*)&wlds[j * 88 + c * 8] =
                *(const uint4*)(Wu + (size_t)(jbase + j) * DIM + c * 8);
        }
        __syncthreads();
#pragma unroll
        for (int t2 = 0; t2 < 2; t2++) {
            const int jl = (wv * 2 + t2) * 16 + l15;
            const short8 b0 = *(const short8*)&wlds[jl * 88 + quad * 8];
            const short8 b1 = *(const short8*)&wlds[jl * 88 + 32 + quad * 8];
#pragma unroll
            for (int rs = 0; rs < 4; rs++) {
                f32x4 acc = {0.f, 0.f, 0.f, 0.f};
                acc = __builtin_amdgcn_mfma_f32_16x16x32_bf16(afrag[rs][0], b0, acc, 0, 0, 0);
                acc = __builtin_amdgcn_mfma_f32_16x16x32_bf16(afrag[rs][1], b1, acc, 0, 0, 0);
                // acc[r] = EXP2_SCALE * u[m] . w[n], m = quad*4+r (+rs*16), n = l15-col
#pragma unroll
                for (int r = 0; r < 4; r++)
                    rowsum[rs][r] += __builtin_amdgcn_exp2f(acc[r]);
            }
        }
        __syncthreads();
    }

    // Reduce across the 16 columns held by lanes sharing a quad.
#pragma unroll
    for (int m = 1; m < 16; m <<= 1)
#pragma unroll
        for (int rs = 0; rs < 4; rs++)
#pragma unroll
            for (int r = 0; r < 4; r++)
                rowsum[rs][r] += __shfl_xor(rowsum[rs][r], m, 64);

    if (l15 == 0) {
#pragma unroll
        for (int rs = 0; rs < 4; rs++)
#pragma unroll
            for (int r = 0; r < 4; r++)
                atomicAdd(&total[rowbase + rs * 16 + quad * 4 + r], rowsum[rs][r]);
    }
}

// Kernel 3: loss[n] = log(total[n] + EPS) - p[n]; out = mean.
__global__ __launch_bounds__(1024) void finalize_kernel(
    const float* __restrict__ total, const float* __restrict__ p,
    float* __restrict__ out)
{
    __shared__ float red[16];
    float s = 0.0f;
    for (int idx = threadIdx.x; idx < NROWS; idx += 1024)
        s += logf(total[idx] + EPS) - p[idx];
#pragma unroll
    for (int m = 1; m < 64; m <<= 1) s += __shfl_xor(s, m, 64);
    if ((threadIdx.x & 63) == 0) red[threadIdx.x >> 6] = s;
    __syncthreads();
    if (threadIdx.x == 0) {
        float t = 0.0f;
#pragma unroll
        for (int k = 0; k < 16; k++) t += red[k];
        out[0] = t * (1.0f / (float)NROWS);
    }
}

extern "C" void kernel_launch(void* const* d_in, const int* in_sizes, int n_in,
                              void* d_out, int out_size, void* d_ws, size_t ws_size,
                              hipStream_t stream) {
    const float* u = (const float*)d_in[0];
    const float* v = (const float*)d_in[1];

    char* ws = (char*)d_ws;
    __hip_bfloat16* a = (__hip_bfloat16*)(ws);                                  // 2 MB
    __hip_bfloat16* w = (__hip_bfloat16*)(ws + (size_t)NROWS * DIM * 2);        // 2 MB
    float* p   = (float*)(ws + (size_t)NROWS * DIM * 4);                        // 64 KB
    float* tot = (float*)(ws + (size_t)NROWS * DIM * 4 + (size_t)NROWS * 4);    // 64 KB

    hipMemsetAsync(tot, 0, NROWS * sizeof(float), stream);
    prep_kernel<<<NROWS / 4, 256, 0, stream>>>(u, v, a, w, p);
    score_kernel<<<512, 256, 0, stream>>>(a, w, tot);
    finalize_kernel<<<1, 1024, 0, stream>>>(tot, p, (float*)d_out);
}

// Round 2
// 139.285 us; speedup vs baseline: 1.2171x; 1.2171x over previous
//
#include <hip/hip_runtime.h>
#include <hip/hip_bf16.h>

#define NROWS 16384
#define DIM 64

static constexpr float TAU = 0.28f;
static constexpr float EPS = 1e-8f;
// exp(x/TAU) = exp2(x * EXP2_SCALE)
static constexpr float EXP2_SCALE = (float)(1.0 / (0.28 * 0.6931471805599453));
static constexpr float LN2F = 0.69314718055994530942f;

using short8 = __attribute__((ext_vector_type(8))) short;
using f32x4  = __attribute__((ext_vector_type(4))) float;

// Kernel 1: per-row L2 normalize; emit A = bf16(EXP2_SCALE * u_norm),
// W = bf16(u_norm + i_norm), p[n] = (u_norm . i_norm)/TAU, and zero total[n]
// (replaces a separate memset dispatch).
__global__ __launch_bounds__(256) void prep_kernel(
    const float* __restrict__ u, const float* __restrict__ v,
    __hip_bfloat16* __restrict__ a_out, __hip_bfloat16* __restrict__ w_out,
    float* __restrict__ p_out, float* __restrict__ total)
{
    const int lane = threadIdx.x & 63;
    const int wv   = threadIdx.x >> 6;
    const int row  = blockIdx.x * 4 + wv;

    const float uu = u[row * DIM + lane];
    const float ii = v[row * DIM + lane];
    float su = uu * uu, si = ii * ii, sd = uu * ii;
#pragma unroll
    for (int m = 1; m < 64; m <<= 1) {
        su += __shfl_xor(su, m, 64);
        si += __shfl_xor(si, m, 64);
        sd += __shfl_xor(sd, m, 64);
    }
    const float inv_u = 1.0f / fmaxf(sqrtf(su), 1e-12f);
    const float inv_i = 1.0f / fmaxf(sqrtf(si), 1e-12f);
    const float un = uu * inv_u;
    const float in = ii * inv_i;
    a_out[row * DIM + lane] = __float2bfloat16(EXP2_SCALE * un);
    w_out[row * DIM + lane] = __float2bfloat16(un + in);
    if (lane == 0) {
        p_out[row] = sd * inv_u * inv_i * (1.0f / TAU);
        total[row] = 0.0f;
    }
}

// Kernel 2: fused GEMM + exp + row-sum, barrier-free.
// Grid: 4096 blocks = 256 row-blocks (64 rows) x 16 column splits (1024 cols).
// Block: 256 threads = 4 waves; each wave owns all 64 rows (A-frags resident
// in VGPRs) and 256 disjoint columns (16 col-groups of 16), loading its
// B-fragments directly from global (W is 2 MB -> L2-resident), prefetched
// one group ahead. No LDS in the hot loop, no barriers.
__global__ __launch_bounds__(256, 4) void score_kernel(
    const __hip_bfloat16* __restrict__ A, const __hip_bfloat16* __restrict__ W,
    float* __restrict__ total)
{
    const int tid  = threadIdx.x;
    const int lane = tid & 63;
    const int wv   = tid >> 6;
    const int l15  = lane & 15;
    const int quad = lane >> 4;
    const int rb   = blockIdx.x >> 4;     // 256 row-blocks
    const int cs   = blockIdx.x & 15;     // 16 column splits
    const int rowbase = rb * 64;
    const int colbase = cs * 1024 + wv * 256;

    const ushort* Au = (const ushort*)A;
    const ushort* Wu = (const ushort*)W;

    // A fragments: rows rowbase + rs*16 + l15, k = kk*32 + quad*8 + [0..7]
    short8 afrag[4][2];
#pragma unroll
    for (int rs = 0; rs < 4; rs++)
#pragma unroll
        for (int kk = 0; kk < 2; kk++)
            afrag[rs][kk] = *(const short8*)(
                Au + (size_t)(rowbase + rs * 16 + l15) * DIM + kk * 32 + quad * 8);

    float rowsum[4][4];
#pragma unroll
    for (int rs = 0; rs < 4; rs++)
#pragma unroll
        for (int r = 0; r < 4; r++) rowsum[rs][r] = 0.0f;

    // B-fragment base for this lane: column (colbase + g*16 + l15), k-chunk quad*8.
    const ushort* wp = Wu + (size_t)(colbase + l15) * DIM + quad * 8;

    short8 b0 = *(const short8*)(wp);
    short8 b1 = *(const short8*)(wp + 32);
    for (int g = 0; g < 16; g++) {
        const int gn = (g < 15) ? (g + 1) : 15;
        const ushort* np = wp + (size_t)gn * 16 * DIM;
        short8 nb0 = *(const short8*)(np);
        short8 nb1 = *(const short8*)(np + 32);
#pragma unroll
        for (int rs = 0; rs < 4; rs++) {
            f32x4 acc = {0.f, 0.f, 0.f, 0.f};
            acc = __builtin_amdgcn_mfma_f32_16x16x32_bf16(afrag[rs][0], b0, acc, 0, 0, 0);
            acc = __builtin_amdgcn_mfma_f32_16x16x32_bf16(afrag[rs][1], b1, acc, 0, 0, 0);
            // acc[r] = EXP2_SCALE * u[m].w[n]; m = rowbase + rs*16 + quad*4 + r
#pragma unroll
            for (int r = 0; r < 4; r++)
                rowsum[rs][r] += __builtin_amdgcn_exp2f(acc[r]);
        }
        b0 = nb0; b1 = nb1;
    }

    // Reduce across the 16 columns (lanes sharing a quad).
#pragma unroll
    for (int m = 1; m < 16; m <<= 1)
#pragma unroll
        for (int rs = 0; rs < 4; rs++)
#pragma unroll
            for (int r = 0; r < 4; r++)
                rowsum[rs][r] += __shfl_xor(rowsum[rs][r], m, 64);

    // Cross-wave combine in LDS (all 4 waves cover the same 64 rows),
    // then one atomicAdd per row per block.
    __shared__ float part[64][4];
    if (l15 == 0) {
#pragma unroll
        for (int rs = 0; rs < 4; rs++)
#pragma unroll
            for (int r = 0; r < 4; r++)
                part[rs * 16 + quad * 4 + r][wv] = rowsum[rs][r];
    }
    __syncthreads();
    if (tid < 64) {
        const float s = part[tid][0] + part[tid][1] + part[tid][2] + part[tid][3];
        atomicAdd(&total[rowbase + tid], s);
    }
}

// Kernel 3: loss[n] = log(total[n] + EPS) - p[n]; out = mean.
__global__ __launch_bounds__(1024) void finalize_kernel(
    const float* __restrict__ total, const float* __restrict__ p,
    float* __restrict__ out)
{
    __shared__ float red[16];
    float s = 0.0f;
#pragma unroll
    for (int k = 0; k < NROWS / 1024; k++) {
        const int idx = k * 1024 + threadIdx.x;
        s += __log2f(total[idx] + EPS) * LN2F - p[idx];
    }
#pragma unroll
    for (int m = 1; m < 64; m <<= 1) s += __shfl_xor(s, m, 64);
    if ((threadIdx.x & 63) == 0) red[threadIdx.x >> 6] = s;
    __syncthreads();
    if (threadIdx.x == 0) {
        float t = 0.0f;
#pragma unroll
        for (int k = 0; k < 16; k++) t += red[k];
        out[0] = t * (1.0f / (float)NROWS);
    }
}

extern "C" void kernel_launch(void* const* d_in, const int* in_sizes, int n_in,
                              void* d_out, int out_size, void* d_ws, size_t ws_size,
                              hipStream_t stream) {
    const float* u = (const float*)d_in[0];
    const float* v = (const float*)d_in[1];

    char* ws = (char*)d_ws;
    __hip_bfloat16* a = (__hip_bfloat16*)(ws);                                  // 2 MB
    __hip_bfloat16* w = (__hip_bfloat16*)(ws + (size_t)NROWS * DIM * 2);        // 2 MB
    float* p   = (float*)(ws + (size_t)NROWS * DIM * 4);                        // 64 KB
    float* tot = (float*)(ws + (size_t)NROWS * DIM * 4 + (size_t)NROWS * 4);    // 64 KB

    prep_kernel<<<NROWS / 4, 256, 0, stream>>>(u, v, a, w, p, tot);
    score_kernel<<<4096, 256, 0, stream>>>(a, w, tot);
    finalize_kernel<<<1, 1024, 0, stream>>>(tot, p, (float*)d_out);
}